// Round 11
// baseline (48.698 us; speedup 1.0000x reference)
//
#include <hip/hip_runtime.h>

#define EPS 1e-5f
#define ONE_M_EPS (1.0f - 1e-5f)
#define NROW 2048
#define FF 20
#define DH 64
#define PADW (DH + 4)        // 68: rows stay 16B-aligned, bank-shifted
#define NPAIR (FF * FF)      // 400
#define NPAIR2 (NPAIR + FF)  // + f.Q dots

typedef float v2f __attribute__((ext_vector_type(2)));

__device__ __forceinline__ float frcp(float x) { return __builtin_amdgcn_rcpf(x); }
__device__ __forceinline__ float fsq(float x) { return __builtin_amdgcn_sqrtf(x); }
__device__ __forceinline__ v2f pkfma(v2f a, v2f b, v2f c) {
  return __builtin_elementwise_fma(a, b, c);
}
__device__ __forceinline__ float rdlane(float v, int lane) {
  return __int_as_float(__builtin_amdgcn_readlane(__float_as_int(v), lane));
}

// DPP partial-sum step
template <int CTRL>
__device__ __forceinline__ float dppadd(float x) {
  int t = __builtin_amdgcn_update_dpp(0, __float_as_int(x), CTRL, 0xf, 0xf, false);
  return x + __int_as_float(t);
}
// full 64-lane sum, broadcast via readlane(63)
__device__ __forceinline__ float wredb(float v) {
  v = dppadd<0x111>(v);
  v = dppadd<0x112>(v);
  v = dppadd<0x114>(v);
  v = dppadd<0x118>(v);
  v = dppadd<0x142>(v);
  v = dppadd<0x143>(v);
  return rdlane(v, 63);
}

__device__ __forceinline__ float ftanh(float x) {  // general
  float ax = fabsf(x);
  float e = __expf(-2.f * ax);
  float t = (1.f - e) * frcp(1.f + e);
  return copysignf(t, x);
}

__device__ __forceinline__ float ftanhp(float x) {  // x >= 0
  float e = __expf(-2.f * x);
  return (1.f - e) * frcp(1.f + e);
}

__device__ __forceinline__ float fatanh(float x) {  // x in [0, 1-EPS]
  return 0.5f * __logf((1.f + x) * frcp(1.f - x));
}

__device__ __forceinline__ float clampn(float x) {
  return fminf(fmaxf(x, EPS), ONE_M_EPS);
}

// exp(-acosh(arg)) = 1/(arg + sqrt(arg^2-1)), exact
__device__ __forceinline__ float expnacosh(float arg) {
  return frcp(arg + fsq(fmaxf(arg * arg - 1.f, 0.f)));
}

// packed 64-elem dot of two 16B-aligned rows
__device__ __forceinline__ float dot64(const float* __restrict__ a,
                                       const float* __restrict__ b) {
  const float4* ap = (const float4*)a;
  const float4* bp = (const float4*)b;
  v2f acc = {0.f, 0.f};
#pragma unroll
  for (int kk = 0; kk < DH / 4; ++kk) {
    float4 x = ap[kk];
    float4 y = bp[kk];
    acc = pkfma(v2f{x.x, x.y}, v2f{y.x, y.y}, acc);
    acc = pkfma(v2f{x.z, x.w}, v2f{y.z, y.w}, acc);
  }
  return acc.x + acc.y;
}

struct FeatParams {
  const float *emb0, *emb1, *win, *bin;
  float* fout;
};

struct ModeParams {
  const float* f;
  const int *Didx, *Qidx;
  const float *q1p, *qp, *qqp, *aw1, *ab1, *aw2, *wout, *bout;
  float* out;
};

__global__ __launch_bounds__(64) void feat_kernel(const int* __restrict__ x,
                                                  FeatParams ps, FeatParams pc) {
  const int bid = blockIdx.x;
  const int mode = bid >= NROW;
  const FeatParams P = mode ? pc : ps;
  const int n = bid - mode * NROW;
  const int l = threadIdx.x;
  __shared__ float u[DH];
  int x0 = x[n * 2 + 0];
  int x1 = x[n * 2 + 1];
  u[l] = (l < 32) ? P.emb0[x0 * 32 + l] : P.emb1[x1 * 32 + (l - 32)];
  __syncthreads();
  v2f acc2 = {P.bin[l], 0.f};
#pragma unroll
  for (int k = 0; k < DH; k += 2) {
    v2f uv = *(const v2f*)&u[k];
    v2f wv = {P.win[k * DH + l], P.win[(k + 1) * DH + l]};
    acc2 = pkfma(uv, wv, acc2);
  }
  float acc = acc2.x + acc2.y;
  float a2 = wredb(acc * acc);
  float nn = fsq(a2 + 1e-15f);
  P.fout[n * DH + l] = ftanhp(nn) * frcp(fmaxf(nn, EPS)) * acc;
}

// One wave per (mode,row). Block == wave: every __syncthreads is a cheap
// single-wave barrier (waitcnt only) -> no cross-wave idle phases.
__global__ __launch_bounds__(64) void mode_kernel(ModeParams pm0, ModeParams pm1) {
  const int bid = blockIdx.x;
  const int mode = bid >= NROW;
  const ModeParams P = mode ? pm1 : pm0;
  const int n = bid - mode * NROW;
  const int l = threadIdx.x;

  __shared__ alignas(16) float Ds[FF][PADW];  // D rows -> h rows after P5
  __shared__ alignas(16) float Qs[FF][PADW];  // raw Q rows
  __shared__ alignas(16) float fs_[PADW];
  __shared__ alignas(16) float Gm[NPAIR];  // softmax numerators exp(-d)
  __shared__ float Fq[FF];                 // f.Q raw dots
  __shared__ float D2[FF];                 // |D|^2 -> h2 after P5
  __shared__ float FD[FF], X2s[FF];        // fDc, fDc^2|D|^2
  __shared__ float Q2[FF], WQ[FF];         // WQ = atanh(|Q|)/|Q|
  __shared__ float zb[2][DH];
  __shared__ float ub[DH];

  const float* f = P.f;
  float fv = f[n * DH + l];

  // ---- P0: gather tiles (40 coalesced row loads, all in flight) ----
  int di = (l < FF) ? P.Didx[n * FF + l] : 0;
  int qi = (l < FF) ? P.Qidx[n * FF + l] : 0;
#pragma unroll
  for (int i = 0; i < FF; ++i) {
    int ri = __builtin_amdgcn_readlane(di, i);
    int rq = __builtin_amdgcn_readlane(qi, i);
    Ds[i][l] = f[ri * DH + l];
    Qs[i][l] = f[rq * DH + l];
  }
  fs_[l] = fv;
  float f2 = wredb(fv * fv);
  float fnc = clampn(fsq(f2 + 1e-15f));
  float fA = fatanh(fnc);
  float q1 = P.q1p[0], qsc = P.qp[0], qqsc = P.qqp[0];
  __syncthreads();

  // ---- P1: all 40 row norms in ONE dot64 pass (lanes 0-19: D, 32-51: Q) ----
  {
    const bool isD = (l < FF);
    const bool isQ = (l >= 32 && l < 32 + FF);
    const float* rp = isD ? &Ds[l][0] : (isQ ? &Qs[l - 32][0] : &fs_[0]);
    float dot = dot64(rp, rp);
    float nc = clampn(fsq(dot + 1e-15f));
    float at = fatanh(nc);
    if (isD) {
      D2[l] = dot;
      float fd = ftanh(q1 * at) * frcp(nc);  // mob_scalar(D,q1) coefficient
      FD[l] = fd;
      X2s[l] = fd * fd * dot;
    } else if (isQ) {
      Q2[l - 32] = dot;
      WQ[l - 32] = at * frcp(nc);
    }
  }
  __syncthreads();

  // scaled Q columns in registers: qregS[j] = (atanh(|Q_j|)/|Q_j|) * Q_j[l]
  float qregS[FF];
#pragma unroll
  for (int j = 0; j < FF; ++j) qregS[j] = WQ[j] * Qs[j][l];

  // ---- P2: pair dots (raw Q) -> softmax numerators; ~7 dots/lane ----
  for (int p = l; p < NPAIR2; p += 64) {
    int i = p / FF;
    int j = p - i * FF;
    const float* ap = (i < FF) ? &Ds[i][0] : &fs_[0];
    float dot = dot64(ap, &Qs[j][0]);
    if (i < FF) {
      float d2 = D2[i] + Q2[j] - 2.f * dot;
      float den = fmaxf((1.f - D2[i]) * (1.f - Q2[j]), EPS);
      float arg = fmaxf(1.f + 2.f * d2 * frcp(den), 1.f + 1e-7f);
      Gm[p] = expnacosh(arg);
    } else {
      Fq[j] = dot;
    }
  }
  __syncthreads();

  // ---- P5: 20 slots serial (softmax + log0/mob_scalar collapsed) ----
#pragma unroll 1
  for (int i = 0; i < FF; ++i) {
    const float4* gr = (const float4*)(&Gm[i * FF]);
    v2f ss2 = {0.f, 0.f};
    v2f ac2 = {0.f, 0.f};
#pragma unroll
    for (int jq = 0; jq < FF / 4; ++jq) {
      float4 g4 = gr[jq];
      ss2 += v2f{g4.x, g4.y} + v2f{g4.z, g4.w};
      ac2 = pkfma(v2f{g4.x, g4.y}, v2f{qregS[4 * jq + 0], qregS[4 * jq + 1]},
                  ac2);
      ac2 = pkfma(v2f{g4.z, g4.w}, v2f{qregS[4 * jq + 2], qregS[4 * jq + 3]},
                  ac2);
    }
    float acc = (ac2.x + ac2.y) * frcp(ss2.x + ss2.y);
    float dl = Ds[i][l];
    float a2 = wredb(acc * acc);
    float xy0 = wredb(dl * acc);
    float nn = fsq(a2 + 1e-15f);
    float ec = ftanhp(nn) * frcp(fmaxf(nn, EPS));
    float fDc = FD[i];
    float x2 = X2s[i];
    float y2 = ec * ec * a2;
    float xy = fDc * ec * xy0;
    float al = 1.f + 2.f * xy + y2;
    float be = 1.f - x2;
    float rd = frcp(fmaxf(1.f + 2.f * xy + x2 * y2, EPS));
    Ds[i][l] = (al * fDc * dl + be * ec * acc) * rd;
    float h2 = (al * al * x2 + 2.f * al * be * xy + be * be * y2) * rd * rd;
    if (l == 0) D2[i] = h2;  // norm chain deferred to P6
  }
  __syncthreads();

  // ---- P6: aggregates e1 (over H) then e2 (over scaled Q), full wave each --
#pragma unroll
  for (int m = 0; m < 2; ++m) {
    float a1 = 0.f;
    float wh = 1.f;
    if (m == 0) {
      if (l < FF) {
        float h2 = D2[l];
        float nc = clampn(fsq(h2 + 1e-15f));
        wh = fatanh(nc) * frcp(nc);  // log0 weight for H rows
        float dot = dot64(&fs_[0], &Ds[l][0]);
        float d2 = f2 + h2 - 2.f * dot;
        float den = fmaxf((1.f - f2) * (1.f - h2), EPS);
        float arg = fmaxf(1.f + 2.f * d2 * frcp(den), 1.f + 1e-7f);
        a1 = expnacosh(arg);
      }
    } else {
      if (l < FF) {
        float d2 = f2 + Q2[l] - 2.f * Fq[l];
        float den = fmaxf((1.f - f2) * (1.f - Q2[l]), EPS);
        float arg = fmaxf(1.f + 2.f * d2 * frcp(den), 1.f + 1e-7f);
        a1 = expnacosh(arg);
      }
    }
    float s = wredb(a1);
    float c = (l < FF) ? a1 * frcp(s) * wh : 0.f;
    float accE = 0.f;
    if (m == 0) {
#pragma unroll
      for (int j = 0; j < FF; ++j) accE = fmaf(rdlane(c, j), Ds[j][l], accE);
    } else {
#pragma unroll
      for (int j = 0; j < FF; ++j) accE = fmaf(rdlane(c, j), qregS[j], accE);
    }
    float a2 = wredb(accE * accE);
    float nn = fsq(a2 + 1e-15f);
    float ec = ftanhp(nn) * frcp(fmaxf(nn, EPS));
    float nTE = ec * accE;
    float r = (m == 0) ? qsc : qqsc;
    float fsc = ftanh(r * fA) * frcp(fnc);
    float xv = fsc * fv;
    float x2 = fsc * fsc * f2;
    float y2 = ec * ec * a2;
    float xy = wredb(xv * nTE);
    float al = 1.f + 2.f * xy + y2;
    float be = 1.f - x2;
    float rd = frcp(fmaxf(1.f + 2.f * xy + x2 * y2, EPS));
    float ev = (al * xv + be * nTE) * rd;
    float es = (al * al * x2 + 2.f * al * be * xy + be * be * y2) * rd * rd;
    float n1 = clampn(fsq(es + 1e-15f));
    zb[m][l] = fatanh(n1) * frcp(n1) * ev;
  }
  __syncthreads();

  // ---- P7: beta softmax + rst + u ----
  {
    int p_ = l >> 5, c_ = l & 31;
    v2f mm2 = {P.ab1[c_], 0.f};
#pragma unroll
    for (int k = 0; k < DH; k += 2) {
      v2f zv = *(const v2f*)&zb[p_][k];
      v2f av = {P.aw1[k * 32 + c_], P.aw1[(k + 1) * 32 + c_]};
      mm2 = pkfma(zv, av, mm2);
    }
    float tt = ftanh(mm2.x + mm2.y);
    float sr = tt * P.aw2[c_];
    sr = dppadd<0x111>(sr);
    sr = dppadd<0x112>(sr);
    sr = dppadd<0x114>(sr);
    sr = dppadd<0x118>(sr);
    sr = dppadd<0x142>(sr);  // lane31 = sum(0..31), lane63 = sum(32..63)
    float s0 = rdlane(sr, 31);
    float s1 = rdlane(sr, 63);
    float bm = fmaxf(s0, s1);
    float b0 = __expf(s0 - bm), b1 = __expf(s1 - bm);
    float bi = frcp(b0 + b1);
    b0 *= bi;
    b1 *= bi;
    float rv = fmaf(b0, zb[0][l], b1 * zb[1][l]);
    float r2 = wredb(rv * rv);
    float rn = fsq(r2 + 1e-15f);
    float sc = ftanhp(rn) * frcp(fmaxf(rn, EPS));
    float rst = sc * rv;
    float rr = sc * sc * r2;
    float rc = clampn(fsq(rr + 1e-15f));
    ub[l] = fatanh(rc) * frcp(rc) * rst;
  }
  __syncthreads();

  // ---- P8: out = exp0(u @ wout + bout) ----
  {
    v2f oo2 = {0.f, 0.f};
#pragma unroll
    for (int k = 0; k < DH; k += 2) {
      v2f uv = *(const v2f*)&ub[k];
      v2f wv = {P.wout[k * DH + l], P.wout[(k + 1) * DH + l]};
      oo2 = pkfma(uv, wv, oo2);
    }
    float oo = P.bout[l] + oo2.x + oo2.y;
    float o2 = wredb(oo * oo);
    float on = fsq(o2 + 1e-15f);
    P.out[n * DH + l] = ftanhp(on) * frcp(fmaxf(on, EPS)) * oo;
  }
}

extern "C" void kernel_launch(void* const* d_in, const int* in_sizes, int n_in,
                              void* d_out, int out_size, void* d_ws,
                              size_t ws_size, hipStream_t stream) {
  const int* x = (const int*)d_in[0];
  const int* idx_sim = (const int*)d_in[1];
  const int* idx_cor = (const int*)d_in[2];
  const float* p[2][12];
  for (int m = 0; m < 2; ++m)
    for (int k = 0; k < 12; ++k) p[m][k] = (const float*)d_in[3 + m * 12 + k];

  float* fsim = (float*)d_ws;
  float* fcor = fsim + NROW * DH;
  float* out = (float*)d_out;

  FeatParams fps = {p[0][0], p[0][1], p[0][2], p[0][3], fsim};
  FeatParams fpc = {p[1][0], p[1][1], p[1][2], p[1][3], fcor};
  feat_kernel<<<2 * NROW, 64, 0, stream>>>(x, fps, fpc);

  // mode 'sim': D = f[idx_cor], Q = f[idx_sim]; mode 'cor': swapped
  ModeParams m0 = {fsim, idx_cor, idx_sim, p[0][6], p[0][4], p[0][5],
                   p[0][7], p[0][8], p[0][9], p[0][10], p[0][11], out};
  ModeParams m1 = {fcor, idx_sim, idx_cor, p[1][6], p[1][4], p[1][5],
                   p[1][7], p[1][8], p[1][9], p[1][10], p[1][11], out + NROW * DH};
  mode_kernel<<<2 * NROW, 64, 0, stream>>>(m0, m1);
}

// Round 12
// 42.611 us; speedup vs baseline: 1.1429x; 1.1429x over previous
//
#include <hip/hip_runtime.h>

#define EPS 1e-5f
#define ONE_M_EPS (1.0f - 1e-5f)
#define NROW 2048
#define FF 20
#define DH 64
#define PADW (DH + 4)        // 68: rows stay 16B-aligned
#define NPAIR (FF * FF)      // 400
#define NPAIR2 (NPAIR + FF)  // + f.Q dots

typedef float v2f __attribute__((ext_vector_type(2)));

__device__ __forceinline__ float frcp(float x) { return __builtin_amdgcn_rcpf(x); }
__device__ __forceinline__ float fsq(float x) { return __builtin_amdgcn_sqrtf(x); }
__device__ __forceinline__ v2f pkfma(v2f a, v2f b, v2f c) {
  return __builtin_elementwise_fma(a, b, c);
}
__device__ __forceinline__ float rdlane(float v, int lane) {
  return __int_as_float(__builtin_amdgcn_readlane(__float_as_int(v), lane));
}

// DPP partial-sum step
template <int CTRL>
__device__ __forceinline__ float dppadd(float x) {
  int t = __builtin_amdgcn_update_dpp(0, __float_as_int(x), CTRL, 0xf, 0xf, false);
  return x + __int_as_float(t);
}
// full 64-lane sum, broadcast via readlane(63)
__device__ __forceinline__ float wredb(float v) {
  v = dppadd<0x111>(v);
  v = dppadd<0x112>(v);
  v = dppadd<0x114>(v);
  v = dppadd<0x118>(v);
  v = dppadd<0x142>(v);
  v = dppadd<0x143>(v);
  return rdlane(v, 63);
}

__device__ __forceinline__ float ftanh(float x) {  // general
  float ax = fabsf(x);
  float e = __expf(-2.f * ax);
  float t = (1.f - e) * frcp(1.f + e);
  return copysignf(t, x);
}

__device__ __forceinline__ float ftanhp(float x) {  // x >= 0
  float e = __expf(-2.f * x);
  return (1.f - e) * frcp(1.f + e);
}

__device__ __forceinline__ float fatanh(float x) {  // x in [0, 1-EPS]
  return 0.5f * __logf((1.f + x) * frcp(1.f - x));
}

__device__ __forceinline__ float clampn(float x) {
  return fminf(fmaxf(x, EPS), ONE_M_EPS);
}

// exp(-acosh(arg)) = 1/(arg + sqrt(arg^2-1)), exact
__device__ __forceinline__ float expnacosh(float arg) {
  return frcp(arg + fsq(fmaxf(arg * arg - 1.f, 0.f)));
}

// packed 64-elem dot of two 16B-aligned rows
__device__ __forceinline__ float dot64(const float* __restrict__ a,
                                       const float* __restrict__ b) {
  const float4* ap = (const float4*)a;
  const float4* bp = (const float4*)b;
  v2f acc = {0.f, 0.f};
#pragma unroll
  for (int kk = 0; kk < DH / 4; ++kk) {
    float4 x = ap[kk];
    float4 y = bp[kk];
    acc = pkfma(v2f{x.x, x.y}, v2f{y.x, y.y}, acc);
    acc = pkfma(v2f{x.z, x.w}, v2f{y.z, y.w}, acc);
  }
  return acc.x + acc.y;
}

struct FeatParams {
  const float *emb0, *emb1, *win, *bin;
  float* fout;
};

struct ModeParams {
  const float* f;
  const int *Didx, *Qidx;
  const float *q1p, *qp, *qqp, *aw1, *ab1, *aw2, *wout, *bout;
  float* out;
};

__global__ __launch_bounds__(64) void feat_kernel(const int* __restrict__ x,
                                                  FeatParams ps, FeatParams pc) {
  const int bid = blockIdx.x;
  const int mode = bid >= NROW;
  const FeatParams P = mode ? pc : ps;
  const int n = bid - mode * NROW;
  const int l = threadIdx.x;
  __shared__ float u[DH];
  int x0 = x[n * 2 + 0];
  int x1 = x[n * 2 + 1];
  u[l] = (l < 32) ? P.emb0[x0 * 32 + l] : P.emb1[x1 * 32 + (l - 32)];
  __syncthreads();
  v2f acc2 = {P.bin[l], 0.f};
#pragma unroll
  for (int k = 0; k < DH; k += 2) {
    v2f uv = *(const v2f*)&u[k];
    v2f wv = {P.win[k * DH + l], P.win[(k + 1) * DH + l]};
    acc2 = pkfma(uv, wv, acc2);
  }
  float acc = acc2.x + acc2.y;
  float a2 = wredb(acc * acc);
  float nn = fsq(a2 + 1e-15f);
  P.fout[n * DH + l] = ftanhp(nn) * frcp(fmaxf(nn, EPS)) * acc;
}

__global__ __launch_bounds__(256) void mode_kernel(ModeParams pm0,
                                                   ModeParams pm1) {
  const int bid = blockIdx.x;
  const int mode = bid >= NROW;
  const ModeParams P = mode ? pm1 : pm0;
  const int n = bid - mode * NROW;
  const int tid = threadIdx.x;
  const int l = tid & 63;
  const int w = tid >> 6;

  __shared__ alignas(16) float Ds[FF][PADW];  // D rows -> h rows after P5c
  __shared__ alignas(16) float Qs[FF][PADW];  // raw Q rows -> acc rows (P5a)
  __shared__ alignas(16) float fs_[PADW];
  __shared__ alignas(16) float Gm[NPAIR];  // softmax numerators exp(-d)
  __shared__ float Fq[FF];                 // f.Q raw dots
  __shared__ float D2[FF];                 // |D|^2 -> h2 after P5b
  __shared__ float FD[FF], X2s[FF];        // fDc, fDc^2|D|^2
  __shared__ float Q2[FF], WQ[FF];         // WQ = atanh(|Q|)/|Q|
  __shared__ float C1[FF], C2[FF], WH[FF];  // mob_add coeffs, log0(h) weight
  __shared__ float zb[2][DH];
  __shared__ float ub[DH];
  __shared__ float pb[4][DH];

  float (*As)[PADW] = Qs;  // acc rows reuse raw-Q space (dead after P2)

  const float* f = P.f;
  float fv = f[n * DH + l];

  // ---- P0: gather tiles ----
  for (int i = w; i < FF; i += 4) {
    Ds[i][l] = f[P.Didx[n * FF + i] * DH + l];
    Qs[i][l] = f[P.Qidx[n * FF + i] * DH + l];
  }
  if (w == 0) fs_[l] = fv;
  float f2 = wredb(fv * fv);
  float fnc = clampn(fsq(f2 + 1e-15f));
  float fA = fatanh(fnc);
  float q1 = P.q1p[0], qsc = P.qp[0], qqsc = P.qqp[0];
  __syncthreads();

  // ---- P1: row norms + per-row coefficients (wave0: D, wave1: Q) ----
  if (w < 2 && l < FF) {
    const float* rp = (w == 0) ? &Ds[l][0] : &Qs[l][0];
    float dot = dot64(rp, rp);
    float nc = clampn(fsq(dot + 1e-15f));
    float at = fatanh(nc);
    if (w == 0) {
      D2[l] = dot;
      float fd = ftanh(q1 * at) * frcp(nc);  // mob_scalar(D,q1) coefficient
      FD[l] = fd;
      X2s[l] = fd * fd * dot;
    } else {
      Q2[l] = dot;
      WQ[l] = at * frcp(nc);
    }
  }
  __syncthreads();

  // scaled Q columns in registers: qregS[j] = (atanh(|Q_j|)/|Q_j|) * Q_j[l]
  float qregS[FF];
#pragma unroll
  for (int j = 0; j < FF; ++j) qregS[j] = WQ[j] * Qs[j][l];

  // ---- P2: pair dots (raw Q) -> softmax numerators ----
  for (int p = tid; p < NPAIR2; p += 256) {
    int i = p / FF;
    int j = p - i * FF;
    const float* ap = (i < FF) ? &Ds[i][0] : &fs_[0];
    float dot = dot64(ap, &Qs[j][0]);
    if (i < FF) {
      float d2 = D2[i] + Q2[j] - 2.f * dot;
      float den = fmaxf((1.f - D2[i]) * (1.f - Q2[j]), EPS);
      float arg = fmaxf(1.f + 2.f * d2 * frcp(den), 1.f + 1e-7f);
      Gm[p] = expnacosh(arg);
    } else {
      Fq[j] = dot;
    }
  }
  __syncthreads();

  // ---- P5a: per-wave 5 slots, independent weighted sums (no reductions) ----
  float acc5[5];
#pragma unroll
  for (int s = 0; s < 5; ++s) {
    const int i = w + 4 * s;
    const float4* gr = (const float4*)(&Gm[i * FF]);
    v2f ss2 = {0.f, 0.f};
    v2f ac2 = {0.f, 0.f};
#pragma unroll
    for (int jq = 0; jq < FF / 4; ++jq) {
      float4 g4 = gr[jq];
      ss2 += v2f{g4.x, g4.y} + v2f{g4.z, g4.w};
      ac2 = pkfma(v2f{g4.x, g4.y}, v2f{qregS[4 * jq + 0], qregS[4 * jq + 1]},
                  ac2);
      ac2 = pkfma(v2f{g4.z, g4.w}, v2f{qregS[4 * jq + 2], qregS[4 * jq + 3]},
                  ac2);
    }
    float acc = (ac2.x + ac2.y) * frcp(ss2.x + ss2.y);
    acc5[s] = acc;
    As[i][l] = acc;  // overwrite dead raw-Q row space
  }
  __syncthreads();

  // ---- P5b (wave 0): 40 reductions in one dot pass + ONE parallel chain ----
  if (w == 0) {
    const bool isA = (l < FF);
    const bool isX = (l >= 32 && l < 32 + FF);
    const float* pa = isA ? &As[l][0] : (isX ? &As[l - 32][0] : &fs_[0]);
    const float* pc2 = isA ? &As[l][0] : (isX ? &Ds[l - 32][0] : &fs_[0]);
    float dotv = dot64(pa, pc2);       // lanes 0-19: a2_i; 32-51: xy0_i
    float xyv = __shfl(dotv, l + 32, 64);
    if (isA) {
      float a2 = dotv;
      float xy0 = xyv;
      float nn = fsq(a2 + 1e-15f);
      float ec = ftanhp(nn) * frcp(fmaxf(nn, EPS));
      float fDc = FD[l];
      float x2 = X2s[l];
      float y2 = ec * ec * a2;
      float xy = fDc * ec * xy0;
      float al = 1.f + 2.f * xy + y2;
      float be = 1.f - x2;
      float rd = frcp(fmaxf(1.f + 2.f * xy + x2 * y2, EPS));
      C1[l] = al * fDc * rd;
      C2[l] = be * ec * rd;
      float h2 = (al * al * x2 + 2.f * al * be * xy + be * be * y2) * rd * rd;
      D2[l] = h2;
      float nc = clampn(fsq(h2 + 1e-15f));
      WH[l] = fatanh(nc) * frcp(nc);  // log0 weight for H rows (used in P6)
    }
  }
  __syncthreads();

  // ---- P5c: finalize H rows from live registers ----
#pragma unroll
  for (int s = 0; s < 5; ++s) {
    const int i = w + 4 * s;
    Ds[i][l] = fmaf(C1[i], Ds[i][l], C2[i] * acc5[s]);
  }
  __syncthreads();

  // ---- P6: aggregates (wave0: e1 over H; wave1: e2 over scaled Q regs) ----
  if (w < 2) {
    float a1 = 0.f;
    float wh = 1.f;
    if (w == 0) {
      if (l < FF) {
        float h2 = D2[l];
        wh = WH[l];
        float dot = dot64(&fs_[0], &Ds[l][0]);
        float d2 = f2 + h2 - 2.f * dot;
        float den = fmaxf((1.f - f2) * (1.f - h2), EPS);
        float arg = fmaxf(1.f + 2.f * d2 * frcp(den), 1.f + 1e-7f);
        a1 = expnacosh(arg);
      }
    } else {
      if (l < FF) {
        float d2 = f2 + Q2[l] - 2.f * Fq[l];
        float den = fmaxf((1.f - f2) * (1.f - Q2[l]), EPS);
        float arg = fmaxf(1.f + 2.f * d2 * frcp(den), 1.f + 1e-7f);
        a1 = expnacosh(arg);
      }
    }
    float s = wredb(a1);
    float c = (l < FF) ? a1 * frcp(s) * wh : 0.f;  // wave1: weight in qregS
    float accE = 0.f;
    if (w == 0) {
#pragma unroll
      for (int j = 0; j < FF; ++j) accE = fmaf(rdlane(c, j), Ds[j][l], accE);
    } else {
#pragma unroll
      for (int j = 0; j < FF; ++j) accE = fmaf(rdlane(c, j), qregS[j], accE);
    }
    float a2 = wredb(accE * accE);
    float nn = fsq(a2 + 1e-15f);
    float ec = ftanhp(nn) * frcp(fmaxf(nn, EPS));
    float nTE = ec * accE;
    float r = (w == 0) ? qsc : qqsc;
    float fsc = ftanh(r * fA) * frcp(fnc);
    float xv = fsc * fv;
    float x2 = fsc * fsc * f2;
    float y2 = ec * ec * a2;
    float xy = wredb(xv * nTE);
    float al = 1.f + 2.f * xy + y2;
    float be = 1.f - x2;
    float rd = frcp(fmaxf(1.f + 2.f * xy + x2 * y2, EPS));
    float ev = (al * xv + be * nTE) * rd;
    float es = (al * al * x2 + 2.f * al * be * xy + be * be * y2) * rd * rd;
    float n1 = clampn(fsq(es + 1e-15f));
    zb[w][l] = fatanh(n1) * frcp(n1) * ev;
  }
  __syncthreads();

  // ---- P7: beta softmax + rst + u (wave0) ----
  if (w == 0) {
    int p_ = l >> 5, c_ = l & 31;
    v2f mm2 = {P.ab1[c_], 0.f};
#pragma unroll
    for (int k = 0; k < DH; k += 2) {
      v2f zv = *(const v2f*)&zb[p_][k];
      v2f av = {P.aw1[k * 32 + c_], P.aw1[(k + 1) * 32 + c_]};
      mm2 = pkfma(zv, av, mm2);
    }
    float tt = ftanh(mm2.x + mm2.y);
    float sr = tt * P.aw2[c_];
    sr = dppadd<0x111>(sr);
    sr = dppadd<0x112>(sr);
    sr = dppadd<0x114>(sr);
    sr = dppadd<0x118>(sr);
    sr = dppadd<0x142>(sr);  // lane31 = sum(0..31), lane63 = sum(32..63)
    float s0 = rdlane(sr, 31);
    float s1 = rdlane(sr, 63);
    float bm = fmaxf(s0, s1);
    float b0 = __expf(s0 - bm), b1 = __expf(s1 - bm);
    float bi = frcp(b0 + b1);
    b0 *= bi;
    b1 *= bi;
    float rv = fmaf(b0, zb[0][l], b1 * zb[1][l]);
    float r2 = wredb(rv * rv);
    float rn = fsq(r2 + 1e-15f);
    float sc = ftanhp(rn) * frcp(fmaxf(rn, EPS));
    float rst = sc * rv;
    float rr = sc * sc * r2;
    float rc = clampn(fsq(rr + 1e-15f));
    ub[l] = fatanh(rc) * frcp(rc) * rst;
  }
  __syncthreads();

  // ---- P8: out = exp0(u @ wout + bout), k-split over 4 waves ----
  {
    v2f oo2 = {0.f, 0.f};
#pragma unroll
    for (int k = 0; k < DH / 4; k += 2) {
      int kk = w * (DH / 4) + k;
      v2f uv = *(const v2f*)&ub[kk];
      v2f wv = {P.wout[kk * DH + l], P.wout[(kk + 1) * DH + l]};
      oo2 = pkfma(uv, wv, oo2);
    }
    pb[w][l] = oo2.x + oo2.y;
  }
  __syncthreads();
  if (w == 0) {
    float oo = P.bout[l] + ((pb[0][l] + pb[1][l]) + (pb[2][l] + pb[3][l]));
    float o2 = wredb(oo * oo);
    float on = fsq(o2 + 1e-15f);
    P.out[n * DH + l] = ftanhp(on) * frcp(fmaxf(on, EPS)) * oo;
  }
}

extern "C" void kernel_launch(void* const* d_in, const int* in_sizes, int n_in,
                              void* d_out, int out_size, void* d_ws,
                              size_t ws_size, hipStream_t stream) {
  const int* x = (const int*)d_in[0];
  const int* idx_sim = (const int*)d_in[1];
  const int* idx_cor = (const int*)d_in[2];
  const float* p[2][12];
  for (int m = 0; m < 2; ++m)
    for (int k = 0; k < 12; ++k) p[m][k] = (const float*)d_in[3 + m * 12 + k];

  float* fsim = (float*)d_ws;
  float* fcor = fsim + NROW * DH;
  float* out = (float*)d_out;

  FeatParams fps = {p[0][0], p[0][1], p[0][2], p[0][3], fsim};
  FeatParams fpc = {p[1][0], p[1][1], p[1][2], p[1][3], fcor};
  feat_kernel<<<2 * NROW, 64, 0, stream>>>(x, fps, fpc);

  // mode 'sim': D = f[idx_cor], Q = f[idx_sim]; mode 'cor': swapped
  ModeParams m0 = {fsim, idx_cor, idx_sim, p[0][6], p[0][4], p[0][5],
                   p[0][7], p[0][8], p[0][9], p[0][10], p[0][11], out};
  ModeParams m1 = {fcor, idx_sim, idx_cor, p[1][6], p[1][4], p[1][5],
                   p[1][7], p[1][8], p[1][9], p[1][10], p[1][11], out + NROW * DH};
  mode_kernel<<<2 * NROW, 256, 0, stream>>>(m0, m1);
}

// Round 13
// 41.815 us; speedup vs baseline: 1.1646x; 1.0190x over previous
//
#include <hip/hip_runtime.h>

#define EPS 1e-5f
#define ONE_M_EPS (1.0f - 1e-5f)
#define NROW 2048
#define FF 20
#define DH 64
#define PADW (DH + 4)        // 68 floats: rows 16B-aligned
#define PADH 72              // halves: 144B rows, 16B-aligned
#define NPAIR (FF * FF)      // 400
#define NPAIR2 (NPAIR + FF)  // + f.Q dots

typedef float v2f __attribute__((ext_vector_type(2)));
typedef _Float16 v2h __attribute__((ext_vector_type(2)));

__device__ __forceinline__ float frcp(float x) { return __builtin_amdgcn_rcpf(x); }
__device__ __forceinline__ float fsq(float x) { return __builtin_amdgcn_sqrtf(x); }
__device__ __forceinline__ v2f pkfma(v2f a, v2f b, v2f c) {
  return __builtin_elementwise_fma(a, b, c);
}
__device__ __forceinline__ float rdlane(float v, int lane) {
  return __int_as_float(__builtin_amdgcn_readlane(__float_as_int(v), lane));
}

// DPP partial-sum step
template <int CTRL>
__device__ __forceinline__ float dppadd(float x) {
  int t = __builtin_amdgcn_update_dpp(0, __float_as_int(x), CTRL, 0xf, 0xf, false);
  return x + __int_as_float(t);
}
// full 64-lane sum, broadcast via readlane(63)
__device__ __forceinline__ float wredb(float v) {
  v = dppadd<0x111>(v);
  v = dppadd<0x112>(v);
  v = dppadd<0x114>(v);
  v = dppadd<0x118>(v);
  v = dppadd<0x142>(v);
  v = dppadd<0x143>(v);
  return rdlane(v, 63);
}

__device__ __forceinline__ float ftanh(float x) {  // general
  float ax = fabsf(x);
  float e = __expf(-2.f * ax);
  float t = (1.f - e) * frcp(1.f + e);
  return copysignf(t, x);
}

__device__ __forceinline__ float ftanhp(float x) {  // x >= 0
  float e = __expf(-2.f * x);
  return (1.f - e) * frcp(1.f + e);
}

__device__ __forceinline__ float fatanh(float x) {  // x in [0, 1-EPS]
  return 0.5f * __logf((1.f + x) * frcp(1.f - x));
}

__device__ __forceinline__ float clampn(float x) {
  return fminf(fmaxf(x, EPS), ONE_M_EPS);
}

// exp(-acosh(arg)) = 1/(arg + sqrt(arg^2-1)), exact
__device__ __forceinline__ float expnacosh(float arg) {
  return frcp(arg + fsq(fmaxf(arg * arg - 1.f, 0.f)));
}

// packed 64-elem f32 dot of two 16B-aligned rows (dual accumulators)
__device__ __forceinline__ float dot64(const float* __restrict__ a,
                                       const float* __restrict__ b) {
  const float4* ap = (const float4*)a;
  const float4* bp = (const float4*)b;
  v2f accA = {0.f, 0.f}, accB = {0.f, 0.f};
#pragma unroll
  for (int kk = 0; kk < DH / 4; ++kk) {
    float4 x = ap[kk];
    float4 y = bp[kk];
    accA = pkfma(v2f{x.x, x.y}, v2f{y.x, y.y}, accA);
    accB = pkfma(v2f{x.z, x.w}, v2f{y.z, y.w}, accB);
  }
  v2f acc = accA + accB;
  return acc.x + acc.y;
}

// 64-elem f16 dot via v_dot2_f32_f16; rows are 16B-aligned half arrays
__device__ __forceinline__ float dot64h(const _Float16* __restrict__ a,
                                        const _Float16* __restrict__ b) {
  const uint4* ap = (const uint4*)a;
  const uint4* bp = (const uint4*)b;
  float acc0 = 0.f, acc1 = 0.f;
#pragma unroll
  for (int kk = 0; kk < 8; ++kk) {
    uint4 x = ap[kk];
    uint4 y = bp[kk];
    acc0 = __builtin_amdgcn_fdot2(__builtin_bit_cast(v2h, x.x),
                                  __builtin_bit_cast(v2h, y.x), acc0, false);
    acc1 = __builtin_amdgcn_fdot2(__builtin_bit_cast(v2h, x.y),
                                  __builtin_bit_cast(v2h, y.y), acc1, false);
    acc0 = __builtin_amdgcn_fdot2(__builtin_bit_cast(v2h, x.z),
                                  __builtin_bit_cast(v2h, y.z), acc0, false);
    acc1 = __builtin_amdgcn_fdot2(__builtin_bit_cast(v2h, x.w),
                                  __builtin_bit_cast(v2h, y.w), acc1, false);
  }
  return acc0 + acc1;
}

struct FeatParams {
  const float *emb0, *emb1, *win, *bin;
  float* fout;
};

struct ModeParams {
  const float* f;
  const int *Didx, *Qidx;
  const float *q1p, *qp, *qqp, *aw1, *ab1, *aw2, *wout, *bout;
  float* out;
};

__global__ __launch_bounds__(64) void feat_kernel(const int* __restrict__ x,
                                                  FeatParams ps, FeatParams pc) {
  const int bid = blockIdx.x;
  const int mode = bid >= NROW;
  const FeatParams P = mode ? pc : ps;
  const int n = bid - mode * NROW;
  const int l = threadIdx.x;
  __shared__ float u[DH];
  int x0 = x[n * 2 + 0];
  int x1 = x[n * 2 + 1];
  u[l] = (l < 32) ? P.emb0[x0 * 32 + l] : P.emb1[x1 * 32 + (l - 32)];
  __syncthreads();
  v2f acc2 = {P.bin[l], 0.f};
#pragma unroll
  for (int k = 0; k < DH; k += 2) {
    v2f uv = *(const v2f*)&u[k];
    v2f wv = {P.win[k * DH + l], P.win[(k + 1) * DH + l]};
    acc2 = pkfma(uv, wv, acc2);
  }
  float acc = acc2.x + acc2.y;
  float a2 = wredb(acc * acc);
  float nn = fsq(a2 + 1e-15f);
  P.fout[n * DH + l] = ftanhp(nn) * frcp(fmaxf(nn, EPS)) * acc;
}

__global__ __launch_bounds__(256) void mode_kernel(ModeParams pm0,
                                                   ModeParams pm1) {
  const int bid = blockIdx.x;
  const int mode = bid >= NROW;
  const ModeParams P = mode ? pm1 : pm0;
  const int n = bid - mode * NROW;
  const int tid = threadIdx.x;
  const int l = tid & 63;
  const int w = tid >> 6;

  __shared__ alignas(16) float Ds[FF][PADW];  // D rows -> h rows after P5c
  __shared__ alignas(16) float Qs[FF][PADW];  // raw Q rows -> acc rows (P5a)
  __shared__ alignas(16) float fs_[PADW];
  __shared__ alignas(16) _Float16 Dh[FF][PADH];  // f16 copies for P2 dots
  __shared__ alignas(16) _Float16 Qh[FF][PADH];
  __shared__ alignas(16) _Float16 fh[PADH];
  __shared__ alignas(16) float Gm[NPAIR];  // softmax numerators exp(-d)
  __shared__ float Fq[FF];                 // f.Q raw dots
  __shared__ float D2[FF];                 // |D|^2 -> h2 after P5b
  __shared__ float FD[FF], X2s[FF];        // fDc, fDc^2|D|^2
  __shared__ float Q2[FF], WQ[FF];         // WQ = atanh(|Q|)/|Q|
  __shared__ float C1[FF], C2[FF], WH[FF];  // mob_add coeffs, log0(h) weight
  __shared__ float zb[2][DH];
  __shared__ float ub[DH];

  float (*As)[PADW] = Qs;  // acc rows reuse raw-Q space (dead after P2)

  const float* f = P.f;
  float fv = f[n * DH + l];

  // ---- P0: gather tiles (f32 + f16 copies) ----
  for (int i = w; i < FF; i += 4) {
    float dv = f[P.Didx[n * FF + i] * DH + l];
    float qv = f[P.Qidx[n * FF + i] * DH + l];
    Ds[i][l] = dv;
    Qs[i][l] = qv;
    Dh[i][l] = (_Float16)dv;
    Qh[i][l] = (_Float16)qv;
  }
  if (w == 0) {
    fs_[l] = fv;
    fh[l] = (_Float16)fv;
  }
  float f2 = wredb(fv * fv);
  float fnc = clampn(fsq(f2 + 1e-15f));
  float fA = fatanh(fnc);
  float q1 = P.q1p[0], qsc = P.qp[0], qqsc = P.qqp[0];
  __syncthreads();

  // ---- P1: row norms + per-row coefficients (wave0: D, wave1: Q) ----
  if (w < 2 && l < FF) {
    const float* rp = (w == 0) ? &Ds[l][0] : &Qs[l][0];
    float dot = dot64(rp, rp);
    float nc = clampn(fsq(dot + 1e-15f));
    float at = fatanh(nc);
    if (w == 0) {
      D2[l] = dot;
      float fd = ftanh(q1 * at) * frcp(nc);  // mob_scalar(D,q1) coefficient
      FD[l] = fd;
      X2s[l] = fd * fd * dot;
    } else {
      Q2[l] = dot;
      WQ[l] = at * frcp(nc);
    }
  }
  __syncthreads();

  // scaled Q columns in registers: qregS[j] = (atanh(|Q_j|)/|Q_j|) * Q_j[l]
  float qregS[FF];
#pragma unroll
  for (int j = 0; j < FF; ++j) qregS[j] = WQ[j] * Qs[j][l];

  // ---- P2: pair dots in f16 (half the LDS bytes) -> softmax numerators ----
  for (int p = tid; p < NPAIR2; p += 256) {
    int i = p / FF;
    int j = p - i * FF;
    const _Float16* ap = (i < FF) ? &Dh[i][0] : &fh[0];
    float dot = dot64h(ap, &Qh[j][0]);
    if (i < FF) {
      float d2 = D2[i] + Q2[j] - 2.f * dot;
      float den = fmaxf((1.f - D2[i]) * (1.f - Q2[j]), EPS);
      float arg = fmaxf(1.f + 2.f * d2 * frcp(den), 1.f + 1e-7f);
      Gm[p] = expnacosh(arg);
    } else {
      Fq[j] = dot;
    }
  }
  __syncthreads();

  // ---- P5a: per-wave 5 slots, independent weighted sums (no reductions) ----
  float acc5[5];
#pragma unroll
  for (int s = 0; s < 5; ++s) {
    const int i = w + 4 * s;
    const float4* gr = (const float4*)(&Gm[i * FF]);
    v2f ss2 = {0.f, 0.f};
    v2f ac2 = {0.f, 0.f};
#pragma unroll
    for (int jq = 0; jq < FF / 4; ++jq) {
      float4 g4 = gr[jq];
      ss2 += v2f{g4.x, g4.y} + v2f{g4.z, g4.w};
      ac2 = pkfma(v2f{g4.x, g4.y}, v2f{qregS[4 * jq + 0], qregS[4 * jq + 1]},
                  ac2);
      ac2 = pkfma(v2f{g4.z, g4.w}, v2f{qregS[4 * jq + 2], qregS[4 * jq + 3]},
                  ac2);
    }
    float acc = (ac2.x + ac2.y) * frcp(ss2.x + ss2.y);
    acc5[s] = acc;
    As[i][l] = acc;  // overwrite dead raw-Q row space
  }
  __syncthreads();

  // ---- P5b (wave 0): 40 reductions in one dot pass + ONE parallel chain ----
  if (w == 0) {
    const bool isA = (l < FF);
    const bool isX = (l >= 32 && l < 32 + FF);
    const float* pa = isA ? &As[l][0] : (isX ? &As[l - 32][0] : &fs_[0]);
    const float* pc2 = isA ? &As[l][0] : (isX ? &Ds[l - 32][0] : &fs_[0]);
    float dotv = dot64(pa, pc2);  // lanes 0-19: a2_i; 32-51: xy0_i
    float xyv = __shfl(dotv, l + 32, 64);
    if (isA) {
      float a2 = dotv;
      float xy0 = xyv;
      float nn = fsq(a2 + 1e-15f);
      float ec = ftanhp(nn) * frcp(fmaxf(nn, EPS));
      float fDc = FD[l];
      float x2 = X2s[l];
      float y2 = ec * ec * a2;
      float xy = fDc * ec * xy0;
      float al = 1.f + 2.f * xy + y2;
      float be = 1.f - x2;
      float rd = frcp(fmaxf(1.f + 2.f * xy + x2 * y2, EPS));
      C1[l] = al * fDc * rd;
      C2[l] = be * ec * rd;
      float h2 = (al * al * x2 + 2.f * al * be * xy + be * be * y2) * rd * rd;
      D2[l] = h2;
      float nc = clampn(fsq(h2 + 1e-15f));
      WH[l] = fatanh(nc) * frcp(nc);  // log0 weight for H rows (used in P6)
    }
  }
  __syncthreads();

  // ---- P5c: finalize H rows from live registers ----
#pragma unroll
  for (int s = 0; s < 5; ++s) {
    const int i = w + 4 * s;
    Ds[i][l] = fmaf(C1[i], Ds[i][l], C2[i] * acc5[s]);
  }
  __syncthreads();

  // ---- P6: aggregates (wave0: e1 over H; wave1: e2 over scaled Q regs) ----
  if (w < 2) {
    float a1 = 0.f;
    float wh = 1.f;
    if (w == 0) {
      if (l < FF) {
        float h2 = D2[l];
        wh = WH[l];
        float dot = dot64(&fs_[0], &Ds[l][0]);
        float d2 = f2 + h2 - 2.f * dot;
        float den = fmaxf((1.f - f2) * (1.f - h2), EPS);
        float arg = fmaxf(1.f + 2.f * d2 * frcp(den), 1.f + 1e-7f);
        a1 = expnacosh(arg);
      }
    } else {
      if (l < FF) {
        float d2 = f2 + Q2[l] - 2.f * Fq[l];
        float den = fmaxf((1.f - f2) * (1.f - Q2[l]), EPS);
        float arg = fmaxf(1.f + 2.f * d2 * frcp(den), 1.f + 1e-7f);
        a1 = expnacosh(arg);
      }
    }
    float s = wredb(a1);
    float c = (l < FF) ? a1 * frcp(s) * wh : 0.f;  // wave1: weight in qregS
    float accE = 0.f;
    if (w == 0) {
#pragma unroll
      for (int j = 0; j < FF; ++j) accE = fmaf(rdlane(c, j), Ds[j][l], accE);
    } else {
#pragma unroll
      for (int j = 0; j < FF; ++j) accE = fmaf(rdlane(c, j), qregS[j], accE);
    }
    float a2 = wredb(accE * accE);
    float nn = fsq(a2 + 1e-15f);
    float ec = ftanhp(nn) * frcp(fmaxf(nn, EPS));
    float nTE = ec * accE;
    float r = (w == 0) ? qsc : qqsc;
    float fsc = ftanh(r * fA) * frcp(fnc);
    float xv = fsc * fv;
    float x2 = fsc * fsc * f2;
    float y2 = ec * ec * a2;
    float xy = wredb(xv * nTE);
    float al = 1.f + 2.f * xy + y2;
    float be = 1.f - x2;
    float rd = frcp(fmaxf(1.f + 2.f * xy + x2 * y2, EPS));
    float ev = (al * xv + be * nTE) * rd;
    float es = (al * al * x2 + 2.f * al * be * xy + be * be * y2) * rd * rd;
    float n1 = clampn(fsq(es + 1e-15f));
    zb[w][l] = fatanh(n1) * frcp(n1) * ev;
  }
  __syncthreads();

  // ---- P7: beta softmax + rst + u (wave0) ----
  if (w == 0) {
    int p_ = l >> 5, c_ = l & 31;
    v2f mm2 = {P.ab1[c_], 0.f};
#pragma unroll
    for (int k = 0; k < DH; k += 2) {
      v2f zv = *(const v2f*)&zb[p_][k];
      v2f av = {P.aw1[k * 32 + c_], P.aw1[(k + 1) * 32 + c_]};
      mm2 = pkfma(zv, av, mm2);
    }
    float tt = ftanh(mm2.x + mm2.y);
    float sr = tt * P.aw2[c_];
    sr = dppadd<0x111>(sr);
    sr = dppadd<0x112>(sr);
    sr = dppadd<0x114>(sr);
    sr = dppadd<0x118>(sr);
    sr = dppadd<0x142>(sr);  // lane31 = sum(0..31), lane63 = sum(32..63)
    float s0 = rdlane(sr, 31);
    float s1 = rdlane(sr, 63);
    float bm = fmaxf(s0, s1);
    float b0 = __expf(s0 - bm), b1 = __expf(s1 - bm);
    float bi = frcp(b0 + b1);
    b0 *= bi;
    b1 *= bi;
    float rv = fmaf(b0, zb[0][l], b1 * zb[1][l]);
    float r2 = wredb(rv * rv);
    float rn = fsq(r2 + 1e-15f);
    float sc = ftanhp(rn) * frcp(fmaxf(rn, EPS));
    float rst = sc * rv;
    float rr = sc * sc * r2;
    float rc = clampn(fsq(rr + 1e-15f));
    ub[l] = fatanh(rc) * frcp(rc) * rst;
  }
  __syncthreads();

  // ---- P8 (wave0): out = exp0(u @ wout + bout) ----
  if (w == 0) {
    v2f oo2 = {0.f, 0.f};
#pragma unroll
    for (int k = 0; k < DH; k += 2) {
      v2f uv = *(const v2f*)&ub[k];
      v2f wv = {P.wout[k * DH + l], P.wout[(k + 1) * DH + l]};
      oo2 = pkfma(uv, wv, oo2);
    }
    float oo = P.bout[l] + oo2.x + oo2.y;
    float o2 = wredb(oo * oo);
    float on = fsq(o2 + 1e-15f);
    P.out[n * DH + l] = ftanhp(on) * frcp(fmaxf(on, EPS)) * oo;
  }
}

extern "C" void kernel_launch(void* const* d_in, const int* in_sizes, int n_in,
                              void* d_out, int out_size, void* d_ws,
                              size_t ws_size, hipStream_t stream) {
  const int* x = (const int*)d_in[0];
  const int* idx_sim = (const int*)d_in[1];
  const int* idx_cor = (const int*)d_in[2];
  const float* p[2][12];
  for (int m = 0; m < 2; ++m)
    for (int k = 0; k < 12; ++k) p[m][k] = (const float*)d_in[3 + m * 12 + k];

  float* fsim = (float*)d_ws;
  float* fcor = fsim + NROW * DH;
  float* out = (float*)d_out;

  FeatParams fps = {p[0][0], p[0][1], p[0][2], p[0][3], fsim};
  FeatParams fpc = {p[1][0], p[1][1], p[1][2], p[1][3], fcor};
  feat_kernel<<<2 * NROW, 64, 0, stream>>>(x, fps, fpc);

  // mode 'sim': D = f[idx_cor], Q = f[idx_sim]; mode 'cor': swapped
  ModeParams m0 = {fsim, idx_cor, idx_sim, p[0][6], p[0][4], p[0][5],
                   p[0][7], p[0][8], p[0][9], p[0][10], p[0][11], out};
  ModeParams m1 = {fcor, idx_sim, idx_cor, p[1][6], p[1][4], p[1][5],
                   p[1][7], p[1][8], p[1][9], p[1][10], p[1][11], out + NROW * DH};
  mode_kernel<<<2 * NROW, 256, 0, stream>>>(m0, m1);
}

// Round 14
// 40.987 us; speedup vs baseline: 1.1881x; 1.0202x over previous
//
#include <hip/hip_runtime.h>

#define EPS 1e-5f
#define ONE_M_EPS (1.0f - 1e-5f)
#define NROW 2048
#define FF 20
#define DH 64
#define PADW (DH + 4)        // 68 floats: rows 16B-aligned
#define PADH 72              // halves: 144B rows, 16B-aligned
#define NPAIR (FF * FF)      // 400
#define NPAIR2 (NPAIR + FF)  // + f.Q dots

typedef float v2f __attribute__((ext_vector_type(2)));
typedef _Float16 v2h __attribute__((ext_vector_type(2)));

__device__ __forceinline__ float frcp(float x) { return __builtin_amdgcn_rcpf(x); }
__device__ __forceinline__ float fsq(float x) { return __builtin_amdgcn_sqrtf(x); }
__device__ __forceinline__ v2f pkfma(v2f a, v2f b, v2f c) {
  return __builtin_elementwise_fma(a, b, c);
}
__device__ __forceinline__ float rdlane(float v, int lane) {
  return __int_as_float(__builtin_amdgcn_readlane(__float_as_int(v), lane));
}

// DPP partial-sum step
template <int CTRL>
__device__ __forceinline__ float dppadd(float x) {
  int t = __builtin_amdgcn_update_dpp(0, __float_as_int(x), CTRL, 0xf, 0xf, false);
  return x + __int_as_float(t);
}
// full 64-lane sum, broadcast via readlane(63)
__device__ __forceinline__ float wredb(float v) {
  v = dppadd<0x111>(v);
  v = dppadd<0x112>(v);
  v = dppadd<0x114>(v);
  v = dppadd<0x118>(v);
  v = dppadd<0x142>(v);
  v = dppadd<0x143>(v);
  return rdlane(v, 63);
}

__device__ __forceinline__ float ftanh(float x) {  // general
  float ax = fabsf(x);
  float e = __expf(-2.f * ax);
  float t = (1.f - e) * frcp(1.f + e);
  return copysignf(t, x);
}

__device__ __forceinline__ float ftanhp(float x) {  // x >= 0
  float e = __expf(-2.f * x);
  return (1.f - e) * frcp(1.f + e);
}

__device__ __forceinline__ float fatanh(float x) {  // x in [0, 1-EPS]
  return 0.5f * __logf((1.f + x) * frcp(1.f - x));
}

__device__ __forceinline__ float clampn(float x) {
  return fminf(fmaxf(x, EPS), ONE_M_EPS);
}

// exp(-acosh(arg)) = 1/(arg + sqrt(arg^2-1)), exact
__device__ __forceinline__ float expnacosh(float arg) {
  return frcp(arg + fsq(fmaxf(arg * arg - 1.f, 0.f)));
}

// packed 64-elem f32 dot of two 16B-aligned rows (dual accumulators)
__device__ __forceinline__ float dot64(const float* __restrict__ a,
                                       const float* __restrict__ b) {
  const float4* ap = (const float4*)a;
  const float4* bp = (const float4*)b;
  v2f accA = {0.f, 0.f}, accB = {0.f, 0.f};
#pragma unroll
  for (int kk = 0; kk < DH / 4; ++kk) {
    float4 x = ap[kk];
    float4 y = bp[kk];
    accA = pkfma(v2f{x.x, x.y}, v2f{y.x, y.y}, accA);
    accB = pkfma(v2f{x.z, x.w}, v2f{y.z, y.w}, accB);
  }
  v2f acc = accA + accB;
  return acc.x + acc.y;
}

// 64-elem f16 dot via v_dot2_f32_f16; rows are 16B-aligned half arrays
__device__ __forceinline__ float dot64h(const _Float16* __restrict__ a,
                                        const _Float16* __restrict__ b) {
  const uint4* ap = (const uint4*)a;
  const uint4* bp = (const uint4*)b;
  float acc0 = 0.f, acc1 = 0.f;
#pragma unroll
  for (int kk = 0; kk < 8; ++kk) {
    uint4 x = ap[kk];
    uint4 y = bp[kk];
    acc0 = __builtin_amdgcn_fdot2(__builtin_bit_cast(v2h, x.x),
                                  __builtin_bit_cast(v2h, y.x), acc0, false);
    acc1 = __builtin_amdgcn_fdot2(__builtin_bit_cast(v2h, x.y),
                                  __builtin_bit_cast(v2h, y.y), acc1, false);
    acc0 = __builtin_amdgcn_fdot2(__builtin_bit_cast(v2h, x.z),
                                  __builtin_bit_cast(v2h, y.z), acc0, false);
    acc1 = __builtin_amdgcn_fdot2(__builtin_bit_cast(v2h, x.w),
                                  __builtin_bit_cast(v2h, y.w), acc1, false);
  }
  return acc0 + acc1;
}

struct FeatParams {
  const float *emb0, *emb1, *win, *bin;
  float* fout;
};

struct ModeParams {
  const float* f;
  const int *Didx, *Qidx;
  const float *q1p, *qp, *qqp, *aw1, *ab1, *aw2, *wout, *bout;
  float* out;
};

__global__ __launch_bounds__(64) void feat_kernel(const int* __restrict__ x,
                                                  FeatParams ps, FeatParams pc) {
  const int bid = blockIdx.x;
  const int mode = bid >= NROW;
  const FeatParams P = mode ? pc : ps;
  const int n = bid - mode * NROW;
  const int l = threadIdx.x;
  __shared__ float u[DH];
  int x0 = x[n * 2 + 0];
  int x1 = x[n * 2 + 1];
  u[l] = (l < 32) ? P.emb0[x0 * 32 + l] : P.emb1[x1 * 32 + (l - 32)];
  __syncthreads();
  v2f acc2 = {P.bin[l], 0.f};
#pragma unroll
  for (int k = 0; k < DH; k += 2) {
    v2f uv = *(const v2f*)&u[k];
    v2f wv = {P.win[k * DH + l], P.win[(k + 1) * DH + l]};
    acc2 = pkfma(uv, wv, acc2);
  }
  float acc = acc2.x + acc2.y;
  float a2 = wredb(acc * acc);
  float nn = fsq(a2 + 1e-15f);
  P.fout[n * DH + l] = ftanhp(nn) * frcp(fmaxf(nn, EPS)) * acc;
}

__global__ __launch_bounds__(256) void mode_kernel(ModeParams pm0,
                                                   ModeParams pm1) {
  const int bid = blockIdx.x;
  const int mode = bid >= NROW;
  const ModeParams P = mode ? pm1 : pm0;
  const int n = bid - mode * NROW;
  const int tid = threadIdx.x;
  const int l = tid & 63;
  const int w = tid >> 6;

  __shared__ alignas(16) float Hs[FF][PADW];  // H rows (written at P5c)
  __shared__ alignas(16) float fs_[PADW];
  __shared__ alignas(16) _Float16 Dh[FF][PADH];  // f16 D tile
  __shared__ alignas(16) _Float16 Qh[FF][PADH];  // f16 Q tile
  __shared__ alignas(16) _Float16 fh[PADH];
  __shared__ alignas(16) _Float16 Ah[FF][PADH];  // f16 acc rows (P5a -> P5b)
  __shared__ alignas(16) float Gm[NPAIR];  // softmax numerators exp(-d)
  __shared__ float Fq[FF];                 // f.Q dots
  __shared__ float D2[FF];                 // |D|^2 -> h2 after P5b
  __shared__ float FD[FF], X2s[FF];        // fDc, fDc^2|D|^2
  __shared__ float Q2[FF], WQ[FF];         // WQ = atanh(|Q|)/|Q|
  __shared__ float C1[FF], C2[FF], WH[FF];  // mob_add coeffs, log0(h) weight
  __shared__ float zb[2][DH];
  __shared__ float ub[DH];

  const float* f = P.f;
  float fv = f[n * DH + l];

  // ---- P0: gather tiles (f16 only; f32 D/Q never stored) ----
  for (int i = w; i < FF; i += 4) {
    float dv = f[P.Didx[n * FF + i] * DH + l];
    float qv = f[P.Qidx[n * FF + i] * DH + l];
    Dh[i][l] = (_Float16)dv;
    Qh[i][l] = (_Float16)qv;
  }
  if (w == 0) {
    fs_[l] = fv;
    fh[l] = (_Float16)fv;
  }
  float f2 = wredb(fv * fv);
  float fnc = clampn(fsq(f2 + 1e-15f));
  float fA = fatanh(fnc);
  float q1 = P.q1p[0], qsc = P.qp[0], qqsc = P.qqp[0];
  __syncthreads();

  // ---- P1: row norms from f16 self-dots (wave0: D, wave1: Q) ----
  if (w < 2 && l < FF) {
    const _Float16* rp = (w == 0) ? &Dh[l][0] : &Qh[l][0];
    float dot = dot64h(rp, rp);
    float nc = clampn(fsq(dot + 1e-15f));
    float at = fatanh(nc);
    if (w == 0) {
      D2[l] = dot;
      float fd = ftanh(q1 * at) * frcp(nc);  // mob_scalar(D,q1) coefficient
      FD[l] = fd;
      X2s[l] = fd * fd * dot;
    } else {
      Q2[l] = dot;
      WQ[l] = at * frcp(nc);
    }
  }
  __syncthreads();

  // scaled Q columns in registers: qregS[j] = (atanh(|Q_j|)/|Q_j|) * Q_j[l]
  float qregS[FF];
#pragma unroll
  for (int j = 0; j < FF; ++j) qregS[j] = WQ[j] * (float)Qh[j][l];

  // ---- P2: pair dots in f16 -> softmax numerators ----
  for (int p = tid; p < NPAIR2; p += 256) {
    int i = p / FF;
    int j = p - i * FF;
    const _Float16* ap = (i < FF) ? &Dh[i][0] : &fh[0];
    float dot = dot64h(ap, &Qh[j][0]);
    if (i < FF) {
      float d2 = D2[i] + Q2[j] - 2.f * dot;
      float den = fmaxf((1.f - D2[i]) * (1.f - Q2[j]), EPS);
      float arg = fmaxf(1.f + 2.f * d2 * frcp(den), 1.f + 1e-7f);
      Gm[p] = expnacosh(arg);
    } else {
      Fq[j] = dot;
    }
  }
  __syncthreads();

  // ---- P5a: per-wave 5 slots, independent weighted sums (no reductions) ----
  float acc5[5];
#pragma unroll
  for (int s = 0; s < 5; ++s) {
    const int i = w + 4 * s;
    const float4* gr = (const float4*)(&Gm[i * FF]);
    v2f ss2 = {0.f, 0.f};
    v2f ac2 = {0.f, 0.f};
#pragma unroll
    for (int jq = 0; jq < FF / 4; ++jq) {
      float4 g4 = gr[jq];
      ss2 += v2f{g4.x, g4.y} + v2f{g4.z, g4.w};
      ac2 = pkfma(v2f{g4.x, g4.y}, v2f{qregS[4 * jq + 0], qregS[4 * jq + 1]},
                  ac2);
      ac2 = pkfma(v2f{g4.z, g4.w}, v2f{qregS[4 * jq + 2], qregS[4 * jq + 3]},
                  ac2);
    }
    float acc = (ac2.x + ac2.y) * frcp(ss2.x + ss2.y);
    acc5[s] = acc;
    Ah[i][l] = (_Float16)acc;  // f16 copy for P5b dots
  }
  __syncthreads();

  // ---- P5b (wave 0): 40 f16 reductions in one pass + ONE parallel chain ----
  if (w == 0) {
    const bool isA = (l < FF);
    const bool isX = (l >= 32 && l < 32 + FF);
    const _Float16* pa = isA ? &Ah[l][0] : (isX ? &Ah[l - 32][0] : &fh[0]);
    const _Float16* pb = isA ? &Ah[l][0] : (isX ? &Dh[l - 32][0] : &fh[0]);
    float dotv = dot64h(pa, pb);  // lanes 0-19: a2_i; 32-51: xy0_i
    float xyv = __shfl(dotv, l + 32, 64);
    if (isA) {
      float a2 = dotv;
      float xy0 = xyv;
      float nn = fsq(a2 + 1e-15f);
      float ec = ftanhp(nn) * frcp(fmaxf(nn, EPS));
      float fDc = FD[l];
      float x2 = X2s[l];
      float y2 = ec * ec * a2;
      float xy = fDc * ec * xy0;
      float al = 1.f + 2.f * xy + y2;
      float be = 1.f - x2;
      float rd = frcp(fmaxf(1.f + 2.f * xy + x2 * y2, EPS));
      C1[l] = al * fDc * rd;
      C2[l] = be * ec * rd;
      float h2 = (al * al * x2 + 2.f * al * be * xy + be * be * y2) * rd * rd;
      D2[l] = h2;
      float nc = clampn(fsq(h2 + 1e-15f));
      WH[l] = fatanh(nc) * frcp(nc);  // log0 weight for H rows (used in P6)
    }
  }
  __syncthreads();

  // ---- P5c: finalize H rows (f32) from registers + f16 D ----
#pragma unroll
  for (int s = 0; s < 5; ++s) {
    const int i = w + 4 * s;
    Hs[i][l] = fmaf(C1[i], (float)Dh[i][l], C2[i] * acc5[s]);
  }
  __syncthreads();

  // ---- P6: aggregates (wave0: e1 over H; wave1: e2 over scaled Q regs) ----
  if (w < 2) {
    float a1 = 0.f;
    float wh = 1.f;
    if (w == 0) {
      if (l < FF) {
        float h2 = D2[l];
        wh = WH[l];
        float dot = dot64(&fs_[0], &Hs[l][0]);
        float d2 = f2 + h2 - 2.f * dot;
        float den = fmaxf((1.f - f2) * (1.f - h2), EPS);
        float arg = fmaxf(1.f + 2.f * d2 * frcp(den), 1.f + 1e-7f);
        a1 = expnacosh(arg);
      }
    } else {
      if (l < FF) {
        float d2 = f2 + Q2[l] - 2.f * Fq[l];
        float den = fmaxf((1.f - f2) * (1.f - Q2[l]), EPS);
        float arg = fmaxf(1.f + 2.f * d2 * frcp(den), 1.f + 1e-7f);
        a1 = expnacosh(arg);
      }
    }
    float s = wredb(a1);
    float c = (l < FF) ? a1 * frcp(s) * wh : 0.f;  // wave1: weight in qregS
    float accE = 0.f;
    if (w == 0) {
#pragma unroll
      for (int j = 0; j < FF; ++j) accE = fmaf(rdlane(c, j), Hs[j][l], accE);
    } else {
#pragma unroll
      for (int j = 0; j < FF; ++j) accE = fmaf(rdlane(c, j), qregS[j], accE);
    }
    // two independent reduction chains (ILP): a2 and xy0
    float a2 = wredb(accE * accE);
    float xy0w = wredb(fv * accE);
    float nn = fsq(a2 + 1e-15f);
    float ec = ftanhp(nn) * frcp(fmaxf(nn, EPS));
    float nTE = ec * accE;
    float r = (w == 0) ? qsc : qqsc;
    float fsc = ftanh(r * fA) * frcp(fnc);
    float xv = fsc * fv;
    float x2 = fsc * fsc * f2;
    float y2 = ec * ec * a2;
    float xy = fsc * ec * xy0w;  // == wredb(xv * nTE)
    float al = 1.f + 2.f * xy + y2;
    float be = 1.f - x2;
    float rd = frcp(fmaxf(1.f + 2.f * xy + x2 * y2, EPS));
    float ev = (al * xv + be * nTE) * rd;
    float es = (al * al * x2 + 2.f * al * be * xy + be * be * y2) * rd * rd;
    float n1 = clampn(fsq(es + 1e-15f));
    zb[w][l] = fatanh(n1) * frcp(n1) * ev;
  }
  __syncthreads();

  // ---- P7: beta softmax + rst + u (wave0) ----
  if (w == 0) {
    int p_ = l >> 5, c_ = l & 31;
    v2f mm2 = {P.ab1[c_], 0.f};
#pragma unroll
    for (int k = 0; k < DH; k += 2) {
      v2f zv = *(const v2f*)&zb[p_][k];
      v2f av = {P.aw1[k * 32 + c_], P.aw1[(k + 1) * 32 + c_]};
      mm2 = pkfma(zv, av, mm2);
    }
    float tt = ftanh(mm2.x + mm2.y);
    float sr = tt * P.aw2[c_];
    sr = dppadd<0x111>(sr);
    sr = dppadd<0x112>(sr);
    sr = dppadd<0x114>(sr);
    sr = dppadd<0x118>(sr);
    sr = dppadd<0x142>(sr);  // lane31 = sum(0..31), lane63 = sum(32..63)
    float s0 = rdlane(sr, 31);
    float s1 = rdlane(sr, 63);
    float bm = fmaxf(s0, s1);
    float b0 = __expf(s0 - bm), b1 = __expf(s1 - bm);
    float bi = frcp(b0 + b1);
    b0 *= bi;
    b1 *= bi;
    float rv = fmaf(b0, zb[0][l], b1 * zb[1][l]);
    float r2 = wredb(rv * rv);
    float rn = fsq(r2 + 1e-15f);
    float sc = ftanhp(rn) * frcp(fmaxf(rn, EPS));
    float rst = sc * rv;
    float rr = sc * sc * r2;
    float rc = clampn(fsq(rr + 1e-15f));
    ub[l] = fatanh(rc) * frcp(rc) * rst;
  }
  __syncthreads();

  // ---- P8 (wave0): out = exp0(u @ wout + bout) ----
  if (w == 0) {
    v2f oo2 = {0.f, 0.f};
#pragma unroll
    for (int k = 0; k < DH; k += 2) {
      v2f uv = *(const v2f*)&ub[k];
      v2f wv = {P.wout[k * DH + l], P.wout[(k + 1) * DH + l]};
      oo2 = pkfma(uv, wv, oo2);
    }
    float oo = P.bout[l] + oo2.x + oo2.y;
    float o2 = wredb(oo * oo);
    float on = fsq(o2 + 1e-15f);
    P.out[n * DH + l] = ftanhp(on) * frcp(fmaxf(on, EPS)) * oo;
  }
}

extern "C" void kernel_launch(void* const* d_in, const int* in_sizes, int n_in,
                              void* d_out, int out_size, void* d_ws,
                              size_t ws_size, hipStream_t stream) {
  const int* x = (const int*)d_in[0];
  const int* idx_sim = (const int*)d_in[1];
  const int* idx_cor = (const int*)d_in[2];
  const float* p[2][12];
  for (int m = 0; m < 2; ++m)
    for (int k = 0; k < 12; ++k) p[m][k] = (const float*)d_in[3 + m * 12 + k];

  float* fsim = (float*)d_ws;
  float* fcor = fsim + NROW * DH;
  float* out = (float*)d_out;

  FeatParams fps = {p[0][0], p[0][1], p[0][2], p[0][3], fsim};
  FeatParams fpc = {p[1][0], p[1][1], p[1][2], p[1][3], fcor};
  feat_kernel<<<2 * NROW, 64, 0, stream>>>(x, fps, fpc);

  // mode 'sim': D = f[idx_cor], Q = f[idx_sim]; mode 'cor': swapped
  ModeParams m0 = {fsim, idx_cor, idx_sim, p[0][6], p[0][4], p[0][5],
                   p[0][7], p[0][8], p[0][9], p[0][10], p[0][11], out};
  ModeParams m1 = {fcor, idx_sim, idx_cor, p[1][6], p[1][4], p[1][5],
                   p[1][7], p[1][8], p[1][9], p[1][10], p[1][11], out + NROW * DH};
  mode_kernel<<<2 * NROW, 256, 0, stream>>>(m0, m1);
}

// Round 15
// 40.532 us; speedup vs baseline: 1.2015x; 1.0112x over previous
//
#include <hip/hip_runtime.h>

#define EPS 1e-5f
#define ONE_M_EPS (1.0f - 1e-5f)
#define NROW 2048
#define FF 20
#define DH 64
#define PADW (DH + 4)        // 68 floats: rows 16B-aligned
#define PADH 72              // halves: 144B rows, 16B-aligned
#define NPAIR (FF * FF)      // 400
#define NPAIR3 (NPAIR + 2 * FF)  // + f.Q dots + f.D dots

typedef float v2f __attribute__((ext_vector_type(2)));
typedef _Float16 v2h __attribute__((ext_vector_type(2)));

__device__ __forceinline__ float frcp(float x) { return __builtin_amdgcn_rcpf(x); }
__device__ __forceinline__ float fsq(float x) { return __builtin_amdgcn_sqrtf(x); }
__device__ __forceinline__ v2f pkfma(v2f a, v2f b, v2f c) {
  return __builtin_elementwise_fma(a, b, c);
}
__device__ __forceinline__ float rdlane(float v, int lane) {
  return __int_as_float(__builtin_amdgcn_readlane(__float_as_int(v), lane));
}

// DPP partial-sum step
template <int CTRL>
__device__ __forceinline__ float dppadd(float x) {
  int t = __builtin_amdgcn_update_dpp(0, __float_as_int(x), CTRL, 0xf, 0xf, false);
  return x + __int_as_float(t);
}
// full 64-lane sum, broadcast via readlane(63)
__device__ __forceinline__ float wredb(float v) {
  v = dppadd<0x111>(v);
  v = dppadd<0x112>(v);
  v = dppadd<0x114>(v);
  v = dppadd<0x118>(v);
  v = dppadd<0x142>(v);
  v = dppadd<0x143>(v);
  return rdlane(v, 63);
}

__device__ __forceinline__ float ftanh(float x) {  // general
  float ax = fabsf(x);
  float e = __expf(-2.f * ax);
  float t = (1.f - e) * frcp(1.f + e);
  return copysignf(t, x);
}

__device__ __forceinline__ float ftanhp(float x) {  // x >= 0
  float e = __expf(-2.f * x);
  return (1.f - e) * frcp(1.f + e);
}

__device__ __forceinline__ float fatanh(float x) {  // x in [0, 1-EPS]
  return 0.5f * __logf((1.f + x) * frcp(1.f - x));
}

__device__ __forceinline__ float clampn(float x) {
  return fminf(fmaxf(x, EPS), ONE_M_EPS);
}

// exp(-acosh(arg)) = 1/(arg + sqrt(arg^2-1)), exact
__device__ __forceinline__ float expnacosh(float arg) {
  return frcp(arg + fsq(fmaxf(arg * arg - 1.f, 0.f)));
}

// packed 64-elem f32 dot of two 16B-aligned rows (dual accumulators)
__device__ __forceinline__ float dot64(const float* __restrict__ a,
                                       const float* __restrict__ b) {
  const float4* ap = (const float4*)a;
  const float4* bp = (const float4*)b;
  v2f accA = {0.f, 0.f}, accB = {0.f, 0.f};
#pragma unroll
  for (int kk = 0; kk < DH / 4; ++kk) {
    float4 x = ap[kk];
    float4 y = bp[kk];
    accA = pkfma(v2f{x.x, x.y}, v2f{y.x, y.y}, accA);
    accB = pkfma(v2f{x.z, x.w}, v2f{y.z, y.w}, accB);
  }
  v2f acc = accA + accB;
  return acc.x + acc.y;
}

// 64-elem f16 dot via v_dot2_f32_f16; rows are 16B-aligned half arrays
__device__ __forceinline__ float dot64h(const _Float16* __restrict__ a,
                                        const _Float16* __restrict__ b) {
  const uint4* ap = (const uint4*)a;
  const uint4* bp = (const uint4*)b;
  float acc0 = 0.f, acc1 = 0.f;
#pragma unroll
  for (int kk = 0; kk < 8; ++kk) {
    uint4 x = ap[kk];
    uint4 y = bp[kk];
    acc0 = __builtin_amdgcn_fdot2(__builtin_bit_cast(v2h, x.x),
                                  __builtin_bit_cast(v2h, y.x), acc0, false);
    acc1 = __builtin_amdgcn_fdot2(__builtin_bit_cast(v2h, x.y),
                                  __builtin_bit_cast(v2h, y.y), acc1, false);
    acc0 = __builtin_amdgcn_fdot2(__builtin_bit_cast(v2h, x.z),
                                  __builtin_bit_cast(v2h, y.z), acc0, false);
    acc1 = __builtin_amdgcn_fdot2(__builtin_bit_cast(v2h, x.w),
                                  __builtin_bit_cast(v2h, y.w), acc1, false);
  }
  return acc0 + acc1;
}

struct FeatParams {
  const float *emb0, *emb1, *win, *bin;
  float* fout;
};

struct ModeParams {
  const float* f;
  const int *Didx, *Qidx;
  const float *q1p, *qp, *qqp, *aw1, *ab1, *aw2, *wout, *bout;
  float* out;
};

__global__ __launch_bounds__(64) void feat_kernel(const int* __restrict__ x,
                                                  FeatParams ps, FeatParams pc) {
  const int bid = blockIdx.x;
  const int mode = bid >= NROW;
  const FeatParams P = mode ? pc : ps;
  const int n = bid - mode * NROW;
  const int l = threadIdx.x;
  __shared__ float u[DH];
  int x0 = x[n * 2 + 0];
  int x1 = x[n * 2 + 1];
  u[l] = (l < 32) ? P.emb0[x0 * 32 + l] : P.emb1[x1 * 32 + (l - 32)];
  __syncthreads();
  v2f acc2 = {P.bin[l], 0.f};
#pragma unroll
  for (int k = 0; k < DH; k += 2) {
    v2f uv = *(const v2f*)&u[k];
    v2f wv = {P.win[k * DH + l], P.win[(k + 1) * DH + l]};
    acc2 = pkfma(uv, wv, acc2);
  }
  float acc = acc2.x + acc2.y;
  float a2 = wredb(acc * acc);
  float nn = fsq(a2 + 1e-15f);
  P.fout[n * DH + l] = ftanhp(nn) * frcp(fmaxf(nn, EPS)) * acc;
}

__global__ __launch_bounds__(256) void mode_kernel(ModeParams pm0,
                                                   ModeParams pm1) {
  const int bid = blockIdx.x;
  const int mode = bid >= NROW;
  const ModeParams P = mode ? pm1 : pm0;
  const int n = bid - mode * NROW;
  const int tid = threadIdx.x;
  const int l = tid & 63;
  const int w = tid >> 6;

  __shared__ alignas(16) float Hs[FF][PADW];  // H rows (written at P5c)
  __shared__ alignas(16) float fs_[PADW];
  __shared__ alignas(16) _Float16 Dh[FF][PADH];  // f16 D tile
  __shared__ alignas(16) _Float16 Qh[FF][PADH];  // f16 Q tile
  __shared__ alignas(16) _Float16 fh[PADH];
  __shared__ alignas(16) _Float16 Ah[FF][PADH];  // f16 acc rows (P5a -> P5b)
  __shared__ alignas(16) float Gm[NPAIR];  // softmax numerators exp(-d)
  __shared__ float Fq[FF];                 // f.Q dots
  __shared__ float Fd[FF];                 // f.D dots
  __shared__ float FH[FF];                 // f.h dots (algebraic, P5b)
  __shared__ float D2[FF];                 // |D|^2 -> h2 after P5b
  __shared__ float FDc[FF], X2s[FF];       // fDc, fDc^2|D|^2
  __shared__ float Q2[FF], WQ[FF];         // WQ = atanh(|Q|)/|Q|
  __shared__ float C1[FF], C2[FF], WH[FF];  // mob_add coeffs, log0(h) weight
  __shared__ float zb[2][DH];
  __shared__ float ub[DH];

  const float* f = P.f;
  float fv = f[n * DH + l];

  // ---- P0: gather tiles (f16 only; f32 D/Q never stored) ----
  for (int i = w; i < FF; i += 4) {
    float dv = f[P.Didx[n * FF + i] * DH + l];
    float qv = f[P.Qidx[n * FF + i] * DH + l];
    Dh[i][l] = (_Float16)dv;
    Qh[i][l] = (_Float16)qv;
  }
  if (w == 0) {
    fs_[l] = fv;
    fh[l] = (_Float16)fv;
  }
  float f2 = wredb(fv * fv);
  float fnc = clampn(fsq(f2 + 1e-15f));
  float fA = fatanh(fnc);
  float q1 = P.q1p[0], qsc = P.qp[0], qqsc = P.qqp[0];
  __syncthreads();

  // ---- P1: row norms from f16 self-dots (wave0: D, wave1: Q) ----
  if (w < 2 && l < FF) {
    const _Float16* rp = (w == 0) ? &Dh[l][0] : &Qh[l][0];
    float dot = dot64h(rp, rp);
    float nc = clampn(fsq(dot + 1e-15f));
    float at = fatanh(nc);
    if (w == 0) {
      D2[l] = dot;
      float fd = ftanh(q1 * at) * frcp(nc);  // mob_scalar(D,q1) coefficient
      FDc[l] = fd;
      X2s[l] = fd * fd * dot;
    } else {
      Q2[l] = dot;
      WQ[l] = at * frcp(nc);
    }
  }
  __syncthreads();

  // scaled Q columns in registers: qregS[j] = (atanh(|Q_j|)/|Q_j|) * Q_j[l]
  float qregS[FF];
#pragma unroll
  for (int j = 0; j < FF; ++j) qregS[j] = WQ[j] * (float)Qh[j][l];

  // ---- P2: pair dots in f16 -> softmax numerators (+ f.Q, f.D dots) ----
  for (int p = tid; p < NPAIR3; p += 256) {
    int i = p / FF;
    int j = p - i * FF;
    const _Float16* ap;
    const _Float16* bp;
    if (p < NPAIR) {
      ap = &Dh[i][0];
      bp = &Qh[j][0];
    } else if (p < NPAIR + FF) {
      ap = &fh[0];
      bp = &Qh[p - NPAIR][0];
    } else {
      ap = &fh[0];
      bp = &Dh[p - NPAIR - FF][0];
    }
    float dot = dot64h(ap, bp);
    if (p < NPAIR) {
      float d2 = D2[i] + Q2[j] - 2.f * dot;
      float den = fmaxf((1.f - D2[i]) * (1.f - Q2[j]), EPS);
      float arg = fmaxf(1.f + 2.f * d2 * frcp(den), 1.f + 1e-7f);
      Gm[p] = expnacosh(arg);
    } else if (p < NPAIR + FF) {
      Fq[p - NPAIR] = dot;
    } else {
      Fd[p - NPAIR - FF] = dot;
    }
  }
  __syncthreads();

  // ---- P5a: per-wave 5 slots, independent weighted sums (no reductions) ----
  float acc5[5];
#pragma unroll
  for (int s = 0; s < 5; ++s) {
    const int i = w + 4 * s;
    const float4* gr = (const float4*)(&Gm[i * FF]);
    v2f ss2 = {0.f, 0.f};
    v2f ac2 = {0.f, 0.f};
#pragma unroll
    for (int jq = 0; jq < FF / 4; ++jq) {
      float4 g4 = gr[jq];
      ss2 += v2f{g4.x, g4.y} + v2f{g4.z, g4.w};
      ac2 = pkfma(v2f{g4.x, g4.y}, v2f{qregS[4 * jq + 0], qregS[4 * jq + 1]},
                  ac2);
      ac2 = pkfma(v2f{g4.z, g4.w}, v2f{qregS[4 * jq + 2], qregS[4 * jq + 3]},
                  ac2);
    }
    float acc = (ac2.x + ac2.y) * frcp(ss2.x + ss2.y);
    acc5[s] = acc;
    Ah[i][l] = (_Float16)acc;  // f16 copy for P5b dots
  }
  __syncthreads();

  // ---- P5b (wave 0): 60 f16 reductions in one pass + ONE parallel chain ----
  // lane groups: 0-19 Ah.Ah (a2), 20-39 Ah.Dh (xy0), 40-59 Ah.fh (f.acc)
  if (w == 0) {
    int r = (l < 20) ? l : ((l < 40) ? l - 20 : ((l < 60) ? l - 40 : 0));
    const _Float16* pa = (l < 60) ? &Ah[r][0] : &fh[0];
    const _Float16* pb =
        (l < 20) ? &Ah[r][0] : ((l < 40) ? &Dh[r][0] : &fh[0]);
    float dotv = dot64h(pa, pb);
    float xyv = __shfl(dotv, l + 20, 64);
    float fav = __shfl(dotv, l + 40, 64);
    if (l < FF) {
      float a2 = dotv;
      float xy0 = xyv;
      float nn = fsq(a2 + 1e-15f);
      float ec = ftanhp(nn) * frcp(fmaxf(nn, EPS));
      float fDc = FDc[l];
      float x2 = X2s[l];
      float y2 = ec * ec * a2;
      float xy = fDc * ec * xy0;
      float al = 1.f + 2.f * xy + y2;
      float be = 1.f - x2;
      float rd = frcp(fmaxf(1.f + 2.f * xy + x2 * y2, EPS));
      float c1 = al * fDc * rd;
      float c2 = be * ec * rd;
      C1[l] = c1;
      C2[l] = c2;
      FH[l] = fmaf(c1, Fd[l], c2 * fav);  // <f, h_l> algebraically
      float h2 = (al * al * x2 + 2.f * al * be * xy + be * be * y2) * rd * rd;
      D2[l] = h2;
      float nc = clampn(fsq(h2 + 1e-15f));
      WH[l] = fatanh(nc) * frcp(nc);  // log0 weight for H rows (used in P6)
    }
  }
  __syncthreads();

  // ---- P5c: finalize H rows (f32) from registers + f16 D ----
#pragma unroll
  for (int s = 0; s < 5; ++s) {
    const int i = w + 4 * s;
    Hs[i][l] = fmaf(C1[i], (float)Dh[i][l], C2[i] * acc5[s]);
  }
  __syncthreads();

  // ---- P6: aggregates (wave0: e1 over H; wave1: e2 over scaled Q regs) ----
  if (w < 2) {
    float a1 = 0.f;
    float wh = 1.f;
    if (w == 0) {
      if (l < FF) {
        float h2 = D2[l];
        wh = WH[l];
        float dot = FH[l];  // algebraic <f,h>: no LDS dot pass
        float d2 = f2 + h2 - 2.f * dot;
        float den = fmaxf((1.f - f2) * (1.f - h2), EPS);
        float arg = fmaxf(1.f + 2.f * d2 * frcp(den), 1.f + 1e-7f);
        a1 = expnacosh(arg);
      }
    } else {
      if (l < FF) {
        float d2 = f2 + Q2[l] - 2.f * Fq[l];
        float den = fmaxf((1.f - f2) * (1.f - Q2[l]), EPS);
        float arg = fmaxf(1.f + 2.f * d2 * frcp(den), 1.f + 1e-7f);
        a1 = expnacosh(arg);
      }
    }
    float s = wredb(a1);
    float c = (l < FF) ? a1 * frcp(s) * wh : 0.f;  // wave1: weight in qregS
    float accE = 0.f;
    if (w == 0) {
#pragma unroll
      for (int j = 0; j < FF; ++j) accE = fmaf(rdlane(c, j), Hs[j][l], accE);
    } else {
#pragma unroll
      for (int j = 0; j < FF; ++j) accE = fmaf(rdlane(c, j), qregS[j], accE);
    }
    // two independent reduction chains (ILP): a2 and xy0
    float a2 = wredb(accE * accE);
    float xy0w = wredb(fv * accE);
    float nn = fsq(a2 + 1e-15f);
    float ec = ftanhp(nn) * frcp(fmaxf(nn, EPS));
    float nTE = ec * accE;
    float r = (w == 0) ? qsc : qqsc;
    float fsc = ftanh(r * fA) * frcp(fnc);
    float xv = fsc * fv;
    float x2 = fsc * fsc * f2;
    float y2 = ec * ec * a2;
    float xy = fsc * ec * xy0w;  // == wredb(xv * nTE)
    float al = 1.f + 2.f * xy + y2;
    float be = 1.f - x2;
    float rd = frcp(fmaxf(1.f + 2.f * xy + x2 * y2, EPS));
    float ev = (al * xv + be * nTE) * rd;
    float es = (al * al * x2 + 2.f * al * be * xy + be * be * y2) * rd * rd;
    float n1 = clampn(fsq(es + 1e-15f));
    zb[w][l] = fatanh(n1) * frcp(n1) * ev;
  }
  __syncthreads();

  // ---- P7: beta softmax + rst + u (wave0) ----
  if (w == 0) {
    int p_ = l >> 5, c_ = l & 31;
    v2f mm2 = {P.ab1[c_], 0.f};
#pragma unroll
    for (int k = 0; k < DH; k += 2) {
      v2f zv = *(const v2f*)&zb[p_][k];
      v2f av = {P.aw1[k * 32 + c_], P.aw1[(k + 1) * 32 + c_]};
      mm2 = pkfma(zv, av, mm2);
    }
    float tt = ftanh(mm2.x + mm2.y);
    float sr = tt * P.aw2[c_];
    sr = dppadd<0x111>(sr);
    sr = dppadd<0x112>(sr);
    sr = dppadd<0x114>(sr);
    sr = dppadd<0x118>(sr);
    sr = dppadd<0x142>(sr);  // lane31 = sum(0..31), lane63 = sum(32..63)
    float s0 = rdlane(sr, 31);
    float s1 = rdlane(sr, 63);
    float bm = fmaxf(s0, s1);
    float b0 = __expf(s0 - bm), b1 = __expf(s1 - bm);
    float bi = frcp(b0 + b1);
    b0 *= bi;
    b1 *= bi;
    float rv = fmaf(b0, zb[0][l], b1 * zb[1][l]);
    float r2 = wredb(rv * rv);
    float rn = fsq(r2 + 1e-15f);
    float sc = ftanhp(rn) * frcp(fmaxf(rn, EPS));
    float rst = sc * rv;
    float rr = sc * sc * r2;
    float rc = clampn(fsq(rr + 1e-15f));
    ub[l] = fatanh(rc) * frcp(rc) * rst;
  }
  __syncthreads();

  // ---- P8 (wave0): out = exp0(u @ wout + bout) ----
  if (w == 0) {
    v2f oo2 = {0.f, 0.f};
#pragma unroll
    for (int k = 0; k < DH; k += 2) {
      v2f uv = *(const v2f*)&ub[k];
      v2f wv = {P.wout[k * DH + l], P.wout[(k + 1) * DH + l]};
      oo2 = pkfma(uv, wv, oo2);
    }
    float oo = P.bout[l] + oo2.x + oo2.y;
    float o2 = wredb(oo * oo);
    float on = fsq(o2 + 1e-15f);
    P.out[n * DH + l] = ftanhp(on) * frcp(fmaxf(on, EPS)) * oo;
  }
}

extern "C" void kernel_launch(void* const* d_in, const int* in_sizes, int n_in,
                              void* d_out, int out_size, void* d_ws,
                              size_t ws_size, hipStream_t stream) {
  const int* x = (const int*)d_in[0];
  const int* idx_sim = (const int*)d_in[1];
  const int* idx_cor = (const int*)d_in[2];
  const float* p[2][12];
  for (int m = 0; m < 2; ++m)
    for (int k = 0; k < 12; ++k) p[m][k] = (const float*)d_in[3 + m * 12 + k];

  float* fsim = (float*)d_ws;
  float* fcor = fsim + NROW * DH;
  float* out = (float*)d_out;

  FeatParams fps = {p[0][0], p[0][1], p[0][2], p[0][3], fsim};
  FeatParams fpc = {p[1][0], p[1][1], p[1][2], p[1][3], fcor};
  feat_kernel<<<2 * NROW, 64, 0, stream>>>(x, fps, fpc);

  // mode 'sim': D = f[idx_cor], Q = f[idx_sim]; mode 'cor': swapped
  ModeParams m0 = {fsim, idx_cor, idx_sim, p[0][6], p[0][4], p[0][5],
                   p[0][7], p[0][8], p[0][9], p[0][10], p[0][11], out};
  ModeParams m1 = {fcor, idx_sim, idx_cor, p[1][6], p[1][4], p[1][5],
                   p[1][7], p[1][8], p[1][9], p[1][10], p[1][11], out + NROW * DH};
  mode_kernel<<<2 * NROW, 256, 0, stream>>>(m0, m1);
}